// Round 8
// baseline (245.687 us; speedup 1.0000x reference)
//
#include <hip/hip_runtime.h>
#include <math.h>

// SIFA fused, MFMA v10.
// v9 neutral: VGPR=60 proves the compiler rematerialized wv[81] as in-loop
// ds_reads -> 324 LDS reads/thread (1 per FMA), lgkm-chain bound. v10:
// (1) k_conv loop interchange: nb4[4px][9] in regs, loop k*j with ONE weight
//     read feeding 4 px-FMAs (81 reads total, 4x fewer), split j 0..3 / 4..8
//     to bound live pressure (~120 VGPR).
// (2) k_main sub-chunked dbuf: Bs[2][20 cells] (same 40KB), 4 chunks; per
//     chunk issue next loads -> MFMA(cur) -> gate+write(next) -> barrier.
// k_fold/k_gate byte-identical to v9 (same channel-major cell map).

#define EPSF 1e-5f
typedef _Float16 v8h __attribute__((ext_vector_type(8)));
typedef __fp16 fp16x2 __attribute__((ext_vector_type(2)));   // cvt_pkrtz native type
typedef float v4f __attribute__((ext_vector_type(4)));

static constexpr int C_ = 64, HW_ = 16384, W_ = 128;
static constexpr int KB_ = 80;                 // K = 640 = 80 cells of 8 f16

// ws float offsets
static constexpr int WS_WFOLD = 0;       // 5184: [c][j][k] folded depthwise weights
static constexpr int WS_SHIFT = 5184;    // 576
static constexpr int WS_BIAS  = 5760;    // 128
static constexpr int WS_GATE  = 5888;    // 512*4 {wa*cgate, 1-wa, -log2e*a_sp, -log2e*b_sp}
static constexpr int WS_PART  = 7936;    // 8b*16cq*8(ch*2+s)*64p = 65536
static constexpr int WS_WH    = 73472;   // 80*128*8 f16 = 40960 floats: Wh[kb][oup][8]
static constexpr int WS_BIMG  = 114688;  // B-image: per batch 128tile*80kb*128px*8 f16
static constexpr size_t BIMG_BATCH_F16 = (size_t)128 * KB_ * 128 * 8;   // 10,485,760
static constexpr size_t BIMG_BATCH_FLT = BIMG_BATCH_F16 / 2;            // 5,242,880

__device__ __forceinline__ float sigmf(float v) { return 1.f / (1.f + __expf(-v)); }

__device__ __forceinline__ unsigned int pk_u32(float a, float b) {
    fp16x2 h = __builtin_amdgcn_cvt_pkrtz(a, b);
    return __builtin_bit_cast(unsigned int, h);
}

// K-slot map (channel-major cells): kb in [0,80): grp=kb/10, r=kb%10,
// tp=r/5, cl=r%5, cbase=grp*8+tp*4.
//   cl<4 : cell = channel cbase+cl, j = e (e=0..7)
//   cl==4: e<4 -> channel cbase+e, j=8 ; e>=4 -> zero pad
__global__ __launch_bounds__(256) void k_fold(
    const float* __restrict__ gen_w,
    const float* __restrict__ gg, const float* __restrict__ gb,
    const float* __restrict__ gm, const float* __restrict__ gv,
    const float* __restrict__ conv_w,
    const float* __restrict__ cg, const float* __restrict__ cb,
    const float* __restrict__ cm, const float* __restrict__ cv,
    float* __restrict__ ws)
{
    int idx = blockIdx.x * 256 + threadIdx.x;
    _Float16* Whp = (_Float16*)(ws + WS_WH);
    if (idx < 81920) {
        // fragment layout: idx = (kb*128 + oup)*8 + e
        int kb = idx >> 10, oup = (idx >> 3) & 127, e = idx & 7;
        int grp = kb / 10, r = kb - grp * 10;
        int tp = r / 5, cl = r - tp * 5;
        int cbase = grp * 8 + tp * 4;
        int c = -1, j = 0;
        if (cl < 4) { c = cbase + cl; j = e; }
        else if (e < 4) { c = cbase + e; j = 8; }
        float v = 0.f;
        if (c >= 0) {
            float s = cg[oup] * rsqrtf(cv[oup] + EPSF);
            v = conv_w[(oup * C_ + c) * 9 + j] * s;
        }
        Whp[idx] = (_Float16)v;
    } else if (idx < 87104) {
        int i = idx - 81920; int ce = i / 9;
        float s = gg[ce] * rsqrtf(gv[ce] + EPSF);
        ws[WS_WFOLD + i] = gen_w[i] * s;
    } else if (idx < 87680) {
        int ce = idx - 87104;
        float s = gg[ce] * rsqrtf(gv[ce] + EPSF);
        ws[WS_SHIFT + ce] = gb[ce] - gm[ce] * s;
    } else if (idx < 87808) {
        int oup = idx - 87680;
        float s = cg[oup] * rsqrtf(cv[oup] + EPSF);
        ws[WS_BIAS + oup] = cb[oup] - cm[oup] * s;
    }
}

// nb*1024 blocks: (bbl, p(64), cq(16)). Wave = one channel of the quad;
// thread = 4 px (rows r0+4i, col). v10: nb4[4][9] register-resident, loop
// k*j so one weight read feeds 4 px-FMAs; j-space split 0..3 / 4..8 to
// bound live VGPRs. Dense 1KB/wave cell stores; j8 cell via 2KB LDS.
__global__ __launch_bounds__(256) void k_conv(
    const float* __restrict__ x, float* __restrict__ ws, int b0)
{
    __shared__ float xs[4][18 * 19];
    __shared__ float wfl[4][96];            // [ch][0..80] wfold, [84..92] shift
    __shared__ unsigned short j8l[4][256];
    int bid = blockIdx.x;
    int cq = bid & 15, p = (bid >> 4) & 63, bbl = bid >> 10;
    int b = b0 + bbl;
    int oh0 = (p >> 3) << 4, ow0 = (p & 7) << 4;
    int t = threadIdx.x;

    for (int i = t; i < 1296; i += 256) {
        int ch = i / 324, rr = i - ch * 324;
        int r = rr / 18, cc = rr - r * 18;
        int yy = oh0 + r - 1, xx = ow0 + cc - 1;
        float v = 0.f;
        if (yy >= 0 && yy < 128 && xx >= 0 && xx < 128)
            v = x[(size_t)(b * C_ + cq * 4 + ch) * HW_ + yy * 128 + xx];
        xs[ch][r * 19 + cc] = v;
    }
    for (int i = t; i < 384; i += 256) {
        int ch = i / 96, k = i - ch * 96;
        int c = cq * 4 + ch;
        float v = 0.f;
        if (k < 81) v = ws[WS_WFOLD + c * 81 + k];
        else if (k >= 84 && k < 93) v = ws[WS_SHIFT + c * 9 + (k - 84)];
        wfl[ch][k] = v;
    }
    __syncthreads();

    int w = __builtin_amdgcn_readfirstlane(t >> 6);   // wave id = channel in quad
    int lane = t & 63, r0 = lane >> 4, col = lane & 15;

    // ---- all 4 px neighborhoods -> registers (36 floats)
    float nb4[4][9];
#pragma unroll
    for (int px = 0; px < 4; ++px)
#pragma unroll
        for (int dy = 0; dy < 3; ++dy)
#pragma unroll
            for (int dx = 0; dx < 3; ++dx)
                nb4[px][dy * 3 + dx] = xs[w][(r0 + 4 * px + dy) * 19 + col + dx];

    float st0 = 0.f, st1 = 0.f;
    unsigned int pkx[4], pky[4], pkz[4], pkw[4];

    {   // ---- j = 0..3 (wv 36 + uv 16 live)
        float wv[36];
#pragma unroll
        for (int i = 0; i < 9; ++i) {
            float4 v4 = *(const float4*)&wfl[w][i * 4];
            wv[i * 4] = v4.x; wv[i * 4 + 1] = v4.y; wv[i * 4 + 2] = v4.z; wv[i * 4 + 3] = v4.w;
        }
        float uv[4][4];
#pragma unroll
        for (int j = 0; j < 4; ++j) {
            float sj = wfl[w][84 + j];
#pragma unroll
            for (int px = 0; px < 4; ++px) uv[px][j] = sj;
        }
#pragma unroll
        for (int k = 0; k < 9; ++k)
#pragma unroll
            for (int j = 0; j < 4; ++j) {
                float ww = wv[j * 9 + k];
#pragma unroll
                for (int px = 0; px < 4; ++px)
                    uv[px][j] = fmaf(ww, nb4[px][k], uv[px][j]);
            }
#pragma unroll
        for (int px = 0; px < 4; ++px) {
            float u0 = fmaxf(uv[px][0], 0.f), u1 = fmaxf(uv[px][1], 0.f);
            float u2 = fmaxf(uv[px][2], 0.f), u3 = fmaxf(uv[px][3], 0.f);
            st0 += u0 + u1 + u2 + u3;
            st1 = fmaf(u0, u0, st1); st1 = fmaf(u1, u1, st1);
            st1 = fmaf(u2, u2, st1); st1 = fmaf(u3, u3, st1);
            pkx[px] = pk_u32(u0, u1); pky[px] = pk_u32(u2, u3);
        }
    }
    {   // ---- j = 4..8 (wv 45 + uv 20 live)
        float wv[45];
#pragma unroll
        for (int i = 0; i < 11; ++i) {
            float4 v4 = *(const float4*)&wfl[w][36 + i * 4];
            wv[i * 4] = v4.x; wv[i * 4 + 1] = v4.y; wv[i * 4 + 2] = v4.z; wv[i * 4 + 3] = v4.w;
        }
        wv[44] = wfl[w][80];
        float uv[4][5];
#pragma unroll
        for (int jj = 0; jj < 5; ++jj) {
            float sj = wfl[w][88 + jj];
#pragma unroll
            for (int px = 0; px < 4; ++px) uv[px][jj] = sj;
        }
#pragma unroll
        for (int k = 0; k < 9; ++k)
#pragma unroll
            for (int jj = 0; jj < 5; ++jj) {
                float ww = wv[jj * 9 + k];
#pragma unroll
                for (int px = 0; px < 4; ++px)
                    uv[px][jj] = fmaf(ww, nb4[px][k], uv[px][jj]);
            }
#pragma unroll
        for (int px = 0; px < 4; ++px) {
            float u4 = fmaxf(uv[px][0], 0.f), u5 = fmaxf(uv[px][1], 0.f);
            float u6 = fmaxf(uv[px][2], 0.f), u7 = fmaxf(uv[px][3], 0.f);
            float u8 = fmaxf(uv[px][4], 0.f);
            st0 += u4 + u5 + u6 + u7 + u8;
            st1 = fmaf(u4, u4, st1); st1 = fmaf(u5, u5, st1);
            st1 = fmaf(u6, u6, st1); st1 = fmaf(u7, u7, st1);
            st1 = fmaf(u8, u8, st1);
            pkz[px] = pk_u32(u4, u5); pkw[px] = pk_u32(u6, u7);
            _Float16 h8 = (_Float16)u8;
            int row16 = r0 + 4 * px;
            j8l[w][row16 * 16 + col] = __builtin_bit_cast(unsigned short, h8);
        }
    }

    // ---- dense 16B stores: 4 cells (one per px)
    int kbBase = (cq >> 1) * 10 + (cq & 1) * 5;
    int tileBase = ((p >> 3) * 2) * 8 + (p & 7);
    _Float16* Bimg = (_Float16*)(ws + WS_BIMG) + (size_t)bbl * BIMG_BATCH_F16;
#pragma unroll
    for (int px = 0; px < 4; ++px) {
        int row16 = r0 + 4 * px;
        int tile = tileBase + (row16 >> 3) * 8;
        int pxi = (row16 & 7) * 16 + col;
        uint4 oc;
        oc.x = pkx[px]; oc.y = pky[px]; oc.z = pkz[px]; oc.w = pkw[px];
        *(uint4*)(Bimg + (size_t)(tile * KB_ + kbBase + w) * 1024 + (size_t)pxi * 8) = oc;
    }
    __syncthreads();

    {   // ---- cell kbBase+4: {ch0 j8, ch1 j8, ch2 j8, ch3 j8, 0,0,0,0}
        int row16 = t >> 4;
        int tile = tileBase + (row16 >> 3) * 8;
        int px = t & 127;
        uint4 oc;
        oc.x = (unsigned int)j8l[0][t] | ((unsigned int)j8l[1][t] << 16);
        oc.y = (unsigned int)j8l[2][t] | ((unsigned int)j8l[3][t] << 16);
        oc.z = 0u; oc.w = 0u;
        *(uint4*)(Bimg + (size_t)(tile * KB_ + kbBase + 4) * 1024 + (size_t)px * 8) = oc;
    }

    // ---- stats: wave = channel, shuffle reduce, lane0 writes part directly
#pragma unroll
    for (int off = 32; off > 0; off >>= 1) {
        st0 += __shfl_down(st0, off, 64);
        st1 += __shfl_down(st1, off, 64);
    }
    if (lane == 0) {
        float* part = ws + WS_PART;
        part[(size_t)((b * 16 + cq) * 8 + w * 2) * 64 + p] = st0;
        part[(size_t)((b * 16 + cq) * 8 + w * 2 + 1) * 64 + p] = st1;
    }
}

__global__ __launch_bounds__(256) void k_gate(
    const float* __restrict__ part,
    const float* __restrict__ cwt, const float* __restrict__ cbs,
    const float* __restrict__ swt, const float* __restrict__ sbs,
    const float* __restrict__ gnw, const float* __restrict__ gnb,
    const float* __restrict__ wadd, float4* __restrict__ gate, int b0, int nb)
{
    int i = blockIdx.x * 256 + threadIdx.x;
    if (i >= nb * 64) return;
    int b = b0 + (i >> 6), c = i & 63;
    const float* pp = part + (size_t)((b * 16 + (c >> 2)) * 8 + (c & 3) * 2) * 64;
    float s1 = 0.f, s2 = 0.f;
#pragma unroll
    for (int q = 0; q < 16; ++q) {
        float4 a = *(const float4*)(pp + q * 4);
        float4 d = *(const float4*)(pp + 64 + q * 4);
        s1 += a.x + a.y + a.z + a.w;
        s2 += d.x + d.y + d.z + d.w;
    }
    const float N = 9.f * 16384.f;
    float mean = s1 / N;
    float var = s2 / N - mean * mean;
    float inv = rsqrtf(var + EPSF);
    int cgi = c & 7;
    float wa = wadd[0];
    float cgt = sigmf(cwt[cgi] * mean + cbs[cgi]);
    const float NL2E = -1.44269504f;   // sigm(t)=rcp(1+exp2(-t*log2e))
    float4 o;
    o.x = wa * cgt;
    o.y = 1.f - wa;
    o.z = NL2E * (swt[cgi] * gnw[cgi] * inv);
    o.w = NL2E * (swt[cgi] * (gnb[cgi] - mean * inv * gnw[cgi]) + sbs[cgi]);
    gate[b * 64 + c] = o;
}

// nb*256 blocks: (bbl, tile, half). M=128 oup x N=64 px, K=640 in 4 chunks
// of 20 cells, double-buffered Bs[2][20*512] (40KB). Per chunk: issue next
// loads -> MFMA(cur) -> gate+ds_write(next) -> barrier. Gate params
// cell-uniform for cl<4; cl==4 gates e0..3 only.
__global__ __launch_bounds__(256, 4) void k_main(
    const float* __restrict__ ws, float* __restrict__ out, int b0)
{
    __shared__ _Float16 Bs[2][20 * 512];   // 2 x 20 KB
    int t = threadIdx.x;
    int bid = blockIdx.x;
    int half = bid & 1, tile = (bid >> 1) & 127, bbl = bid >> 8;
    int b = b0 + bbl;
    int oh0 = (tile >> 3) << 3, ow0 = (tile & 7) << 4;

    int w = __builtin_amdgcn_readfirstlane(t >> 6);
    int lane = t & 63, quad = lane >> 4, l15 = lane & 15;

    const _Float16* Wh = (const _Float16*)(ws + WS_WH);
    const _Float16* Bimg = (const _Float16*)(ws + WS_BIMG)
        + (size_t)bbl * BIMG_BATCH_F16 + (size_t)tile * (KB_ * 1024)
        + (size_t)(half * 64 + lane) * 8;
    const float4* gp = (const float4*)(ws + WS_GATE) + b * 64;

    v4f acc[2][4];
#pragma unroll
    for (int a = 0; a < 2; ++a)
#pragma unroll
        for (int bb = 0; bb < 4; ++bb) acc[a][bb] = (v4f)0.f;

    auto GATE = [&](int kb, uint4 cell) -> uint4 {
        int grp = kb / 10, rr = kb - grp * 10;
        int tp = (rr >= 5) ? 1 : 0, cl = rr - tp * 5;
        int cbase = grp * 8 + tp * 4;
        v8h v = __builtin_bit_cast(v8h, cell);
        uint4 oc;
        if (cl < 4) {                      // wave-uniform branch
            float4 g = gp[cbase + cl];
            float u[8];
#pragma unroll
            for (int e = 0; e < 8; ++e) {
                float f = (float)v[e];
                float ex = __builtin_amdgcn_exp2f(fmaf(g.z, f, g.w));
                u[e] = f * fmaf(g.y, __builtin_amdgcn_rcpf(1.f + ex), g.x);
            }
            oc.x = pk_u32(u[0], u[1]); oc.y = pk_u32(u[2], u[3]);
            oc.z = pk_u32(u[4], u[5]); oc.w = pk_u32(u[6], u[7]);
        } else {                           // j8 cell: e0..3 channels, e4..7 pads
            float4 g0 = gp[cbase], g1 = gp[cbase + 1];
            float4 g2 = gp[cbase + 2], g3 = gp[cbase + 3];
            float u[4];
#pragma unroll
            for (int e = 0; e < 4; ++e) {
                float f = (float)v[e];
                float4 g = (e == 0) ? g0 : ((e == 1) ? g1 : ((e == 2) ? g2 : g3));
                float ex = __builtin_amdgcn_exp2f(fmaf(g.z, f, g.w));
                u[e] = f * fmaf(g.y, __builtin_amdgcn_rcpf(1.f + ex), g.x);
            }
            oc.x = pk_u32(u[0], u[1]); oc.y = pk_u32(u[2], u[3]);
            oc.z = 0u; oc.w = 0u;
        }
        return oc;
    };

    // ---- prologue: stage chunk 0 into Bs[0]
#pragma unroll
    for (int i = 0; i < 5; ++i) {
        int kl = i * 4 + w;
        uint4 cell = *(const uint4*)(Bimg + (size_t)kl * 1024);
        uint4 oc = GATE(kl, cell);
        *(uint4*)(&Bs[0][kl * 512 + lane * 8]) = oc;
    }
    __syncthreads();

#pragma unroll 1
    for (int c = 0; c < 4; ++c) {
        // ---- issue next chunk's global loads (latency hides under MFMA)
        uint4 cin[5];
        if (c < 3) {
#pragma unroll
            for (int i = 0; i < 5; ++i) {
                int kb = (c + 1) * 20 + i * 4 + w;
                cin[i] = *(const uint4*)(Bimg + (size_t)kb * 1024);
            }
        }
        // ---- MFMA on chunk c: 5 K-steps of 32
        const _Float16* bs = Bs[c & 1];
#pragma unroll
        for (int s = 0; s < 5; ++s) {
            int klq = s * 4 + quad;
            int cglob = c * 20 + klq;
            const _Float16* Ap = Wh + ((size_t)cglob * 128 + w * 32 + l15) * 8;
            v8h A0 = *(const v8h*)(Ap);
            v8h A1 = *(const v8h*)(Ap + 128);          // +16 oup rows
            v8h Bf[4];
#pragma unroll
            for (int bb = 0; bb < 4; ++bb)
                Bf[bb] = *(const v8h*)&bs[klq * 512 + (bb * 16 + l15) * 8];
#pragma unroll
            for (int bb = 0; bb < 4; ++bb) {
                acc[0][bb] = __builtin_amdgcn_mfma_f32_16x16x32_f16(A0, Bf[bb], acc[0][bb], 0, 0, 0);
                acc[1][bb] = __builtin_amdgcn_mfma_f32_16x16x32_f16(A1, Bf[bb], acc[1][bb], 0, 0, 0);
            }
        }
        // ---- gate + write next chunk into the other buffer
        if (c < 3) {
            _Float16* bd = Bs[(c + 1) & 1];
#pragma unroll
            for (int i = 0; i < 5; ++i) {
                int kl = i * 4 + w;
                uint4 oc = GATE((c + 1) * 20 + kl, cin[i]);
                *(uint4*)(&bd[kl * 512 + lane * 8]) = oc;
            }
            __syncthreads();
        }
    }

    // ---- epilogue: bias + SiLU; C/D: col=lane&15(px), row=quad*4+reg(oup)
    size_t ob = (size_t)b * 128 * HW_;
#pragma unroll
    for (int a = 0; a < 2; ++a) {
#pragma unroll
        for (int r2 = 0; r2 < 4; ++r2) {
            int oup = w * 32 + a * 16 + quad * 4 + r2;
            float bo = ws[WS_BIAS + oup];
#pragma unroll
            for (int bb = 0; bb < 4; ++bb) {
                int p2 = half * 64 + bb * 16 + l15;
                int py2 = p2 >> 4, px2 = p2 & 15;
                float z = acc[a][bb][r2] + bo;
                out[ob + (size_t)oup * HW_ + (oh0 + py2) * W_ + ow0 + px2] = z * sigmf(z);
            }
        }
    }
}

extern "C" void kernel_launch(void* const* d_in, const int* in_sizes, int n_in,
                              void* d_out, int out_size, void* d_ws, size_t ws_size,
                              hipStream_t stream)
{
    const float* x      = (const float*)d_in[0];
    const float* gen_w  = (const float*)d_in[1];
    const float* gg     = (const float*)d_in[2];
    const float* gb     = (const float*)d_in[3];
    const float* gm     = (const float*)d_in[4];
    const float* gv     = (const float*)d_in[5];
    const float* gnw    = (const float*)d_in[6];
    const float* gnb    = (const float*)d_in[7];
    const float* cwt    = (const float*)d_in[8];
    const float* cbs    = (const float*)d_in[9];
    const float* swt    = (const float*)d_in[10];
    const float* sbs    = (const float*)d_in[11];
    const float* wadd   = (const float*)d_in[12];
    const float* conv_w = (const float*)d_in[13];
    const float* cg2    = (const float*)d_in[14];
    const float* cb2    = (const float*)d_in[15];
    const float* cm2    = (const float*)d_in[16];
    const float* cv2    = (const float*)d_in[17];
    float* ws  = (float*)d_ws;
    float* out = (float*)d_out;

    // pick the largest batch chunk whose B-image fits in ws
    size_t avail = ws_size / 4;   // floats
    int nb = 1;
    const int cands[4] = {8, 4, 2, 1};
    for (int i = 0; i < 4; ++i) {
        if ((size_t)WS_BIMG + (size_t)cands[i] * BIMG_BATCH_FLT <= avail) { nb = cands[i]; break; }
    }

    k_fold<<<343, 256, 0, stream>>>(gen_w, gg, gb, gm, gv, conv_w, cg2, cb2, cm2, cv2, ws);
    for (int b0 = 0; b0 < 8; b0 += nb) {
        k_conv<<<nb * 1024, 256, 0, stream>>>(x, ws, b0);
        k_gate<<<(nb * 64 + 255) / 256, 256, 0, stream>>>(
            ws + WS_PART, cwt, cbs, swt, sbs, gnw, gnb, wadd,
            (float4*)(ws + WS_GATE), b0, nb);
        k_main<<<nb * 256, 256, 0, stream>>>(ws, out, b0);
    }
}